// Round 3
// baseline (58.567 us; speedup 1.0000x reference)
//
#include <hip/hip_runtime.h>
#include <math.h>
#include <float.h>

// VQ-VAE quantizer, round 3: occupancy-first restructure.
// 512 blocks x 256 thr; block = 64 points; wave w: point-group pg=w&1 (32 pts),
// K-half kh=w>>1 (512 codes). Chunk = 32 codes, single-buffered, 39 KB LDS
// -> 4 blocks/CU = 4 waves/SIMD (was 1).
// score(t,k) = x.e - |e|^2/2 via 3 bf16-split MFMAs; per-half approx top-2;
// exact fp32 rescore of 4 candidates (superset of global top-2) -> argmin.

typedef __attribute__((ext_vector_type(8))) short bf16x8;
typedef __attribute__((ext_vector_type(16))) float f32x16;

#define EBUF_OFF  0        // 2 kh x (eh 8KB + el 8KB) = 32768; qt overlays this
#define EH2_OFF   32768    // 4096 B: -0.5*|e|^2 all 1024 codes
#define KCND_OFF  36864    // 4*64 ints
#define D2S_OFF   37888    // 4*64 floats
#define KFIN_OFF  38912    // 64 ints
#define WSUM_OFF  39168    // 4 floats
#define SMEM_BYTES 39184

__device__ __forceinline__ unsigned short f2bf(float f) {
  unsigned u = __float_as_uint(f);
  unsigned r = u + 0x7FFFu + ((u >> 16) & 1u);   // RNE
  return (unsigned short)(r >> 16);
}
__device__ __forceinline__ float bf2f(unsigned short h) {
  return __uint_as_float(((unsigned)h) << 16);
}

typedef __attribute__((address_space(1))) const void gas_t;
typedef __attribute__((address_space(3))) void las_t;
__device__ __forceinline__ void glds16(const void* g, void* l) {
  __builtin_amdgcn_global_load_lds((gas_t*)g, (las_t*)l, 16, 0, 0);
}

// ---- prep: emb f32 -> eh/el bf16 [1024][128] + eh2 = -0.5*|e|^2 (f32) ----
__global__ __launch_bounds__(256)
void vq_prep(const float* __restrict__ emb, unsigned short* __restrict__ ehg,
             unsigned short* __restrict__ elg, float* __restrict__ eh2g) {
  const int tid = threadIdx.x;
  const int r = blockIdx.x * 16 + (tid >> 4);
  const int seg = tid & 15;
  const float* row = emb + (size_t)r * 128 + seg * 8;
  float4 f0 = *(const float4*)&row[0];
  float4 f1 = *(const float4*)&row[4];
  float fv[8] = {f0.x, f0.y, f0.z, f0.w, f1.x, f1.y, f1.z, f1.w};
  bf16x8 H, L;
  float ssq = 0.f;
#pragma unroll
  for (int j = 0; j < 8; ++j) {
    float f = fv[j];
    ssq = fmaf(f, f, ssq);
    unsigned short h = f2bf(f);
    float res = f - bf2f(h);
    H[j] = (short)h;
    L[j] = (short)f2bf(res);
  }
  *(bf16x8*)(ehg + (size_t)r * 128 + seg * 8) = H;
  *(bf16x8*)(elg + (size_t)r * 128 + seg * 8) = L;
#pragma unroll
  for (int off = 1; off < 16; off <<= 1) ssq += __shfl_xor(ssq, off, 64);
  if (seg == 0) eh2g[r] = -0.5f * ssq;
}

__global__ __launch_bounds__(256, 4)
void vq_main(const float* __restrict__ x, const float* __restrict__ emb,
             const unsigned short* __restrict__ ehg,
             const unsigned short* __restrict__ elg,
             const float* __restrict__ eh2g,
             float* __restrict__ out, float* __restrict__ partial) {
  __shared__ __align__(16) char smem[SMEM_BYTES];
  float* eh2s = (float*)(smem + EH2_OFF);
  int*   kcnd = (int*)(smem + KCND_OFF);
  float* d2s  = (float*)(smem + D2S_OFF);
  int*   kfin = (int*)(smem + KFIN_OFF);
  float* wsum = (float*)(smem + WSUM_OFF);

  const int tid = threadIdx.x;
  const int lane = tid & 63;
  const int w = tid >> 6;
  const int pg = w & 1;            // point group (which 32 of the 64 points)
  const int kh = w >> 1;           // codebook half (512 codes)
  const int hf = lane >> 5;        // K-half of the mfma fragment
  const int c32 = lane & 31;       // mfma column = point within group
  const int blk = blockIdx.x;
  const int b = blk >> 5;
  const int t0 = (blk & 31) << 6;
  const int pw = pg * 32 + c32;    // point index within 64-pt tile
  const size_t bOff = (size_t)b * 262144;   // b*128*2048

  char* Leh = smem + kh * 16384;   // this half's chunk buffer (eh 8K | el 8K)

  // ---- issue chunk-0 staging (async) + eh2 quarter ----
  {
    const char* Geh = (const char*)ehg + (size_t)(kh * 16 + 0) * 8192;
    const char* Gel = (const char*)elg + (size_t)(kh * 16 + 0) * 8192;
#pragma unroll
    for (int i = 0; i < 4; ++i) {
      int o = pg * 4096 + i * 1024 + lane * 16;
      int s = o ^ (((o >> 8) & 15) << 4);
      glds16(Geh + s, Leh + pg * 4096 + i * 1024);
      glds16(Gel + s, Leh + 8192 + pg * 4096 + i * 1024);
    }
    glds16((const char*)eh2g + w * 1024 + lane * 16, smem + EH2_OFF + w * 1024);
  }

  // ---- x B-fragments: fp32 global (coalesced per d) -> bf16 hi/lo regs ----
  bf16x8 xh[8], xl[8];
  {
    const float* xp = x + bOff + t0 + pw;
    const int dbase = hf * 8;
#pragma unroll
    for (int ds = 0; ds < 8; ++ds) {
#pragma unroll
      for (int j = 0; j < 8; ++j) {
        float f = xp[(size_t)(ds * 16 + dbase + j) * 2048];
        unsigned short h = f2bf(f);
        float res = f - bf2f(h);
        xh[ds][j] = (short)h;
        xl[ds][j] = (short)f2bf(res);
      }
    }
  }

  __syncthreads();   // chunk 0 + eh2 staged (syncthreads drains vmcnt)

  float v1 = -FLT_MAX, v2 = -FLT_MAX;
  int k1 = 0, k2 = 0;

  for (int c = 0; c < 16; ++c) {
    const int kb = kh * 512 + c * 32;
    // C-init: acc[reg] = -0.5*|e_k|^2, k = kb + (reg&3) + 8*(reg>>2) + 4*hf
    f32x16 acc;
#pragma unroll
    for (int q = 0; q < 4; ++q) {
      float4 v = *(const float4*)&eh2s[kb + 4 * hf + 8 * q];
      acc[4 * q + 0] = v.x; acc[4 * q + 1] = v.y;
      acc[4 * q + 2] = v.z; acc[4 * q + 3] = v.w;
    }
    const int baseo = c32 * 256 + hf * 16;
    const int swz = (c32 & 15) << 4;
#pragma unroll
    for (int ds = 0; ds < 8; ++ds) {
      const int o = (baseo + ds * 32) ^ swz;
      bf16x8 ea = *(const bf16x8*)(Leh + o);
      bf16x8 eb = *(const bf16x8*)(Leh + 8192 + o);
      acc = __builtin_amdgcn_mfma_f32_32x32x16_bf16(ea, xh[ds], acc, 0, 0, 0);
      acc = __builtin_amdgcn_mfma_f32_32x32x16_bf16(ea, xl[ds], acc, 0, 0, 0);
      acc = __builtin_amdgcn_mfma_f32_32x32x16_bf16(eb, xh[ds], acc, 0, 0, 0);
    }
    // running top-2 (maximize; in-lane k ascending, strict > = first occurrence)
#pragma unroll
    for (int r = 0; r < 16; ++r) {
      float s = acc[r];
      int kk = kb + (r & 3) + 8 * (r >> 2) + 4 * hf;
      bool b1 = s > v1;
      bool b2 = s > v2;
      v2 = fmaxf(fminf(s, v1), v2);          // med3(s, v1, v2)
      k2 = b1 ? k1 : (b2 ? kk : k2);
      v1 = fmaxf(v1, s);
      k1 = b1 ? kk : k1;
    }
    __syncthreads();                 // all compute done reading this chunk
    if (c < 15) {                    // stage next chunk into same buffer
      const char* Geh = (const char*)ehg + (size_t)(kh * 16 + c + 1) * 8192;
      const char* Gel = (const char*)elg + (size_t)(kh * 16 + c + 1) * 8192;
#pragma unroll
      for (int i = 0; i < 4; ++i) {
        int o = pg * 4096 + i * 1024 + lane * 16;
        int s = o ^ (((o >> 8) & 15) << 4);
        glds16(Geh + s, Leh + pg * 4096 + i * 1024);
        glds16(Gel + s, Leh + 8192 + pg * 4096 + i * 1024);
      }
    }
    __syncthreads();                 // staged chunk ready
  }

  // ---- merge hf halves -> per-point top-2 for this K-half ----
  float u1 = __shfl_xor(v1, 32, 64); int j1 = __shfl_xor(k1, 32, 64);
  float u2 = __shfl_xor(v2, 32, 64); int j2 = __shfl_xor(k2, 32, 64);
  bool a = (u1 > v1) || (u1 == v1 && j1 < k1);
  int w1k = a ? j1 : k1;
  float lsv = a ? v1 : u1; int lsk = a ? k1 : j1;   // loser's best
  float wsv = a ? u2 : v2; int wsk = a ? j2 : k2;   // winner's second
  bool bb = (lsv > wsv) || (lsv == wsv && lsk < wsk);
  int w2k = bb ? lsk : wsk;
  if (hf == 0) {
    kcnd[(kh * 2 + 0) * 64 + pw] = w1k;
    kcnd[(kh * 2 + 1) * 64 + pw] = w2k;
  }
  __syncthreads();

  // ---- exact fp32 rescore of 4 candidates: thread = (point, cand) ----
  {
    const int p = tid & 63, cand = tid >> 6;
    const int kc = kcnd[cand * 64 + p];
    const float* xc = x + bOff + t0 + p;
    const float* er = emb + (size_t)kc * 128;
    float dsum = 0.f;
#pragma unroll 4
    for (int d4 = 0; d4 < 128; d4 += 4) {
      float4 e4 = *(const float4*)&er[d4];
      float d0 = xc[(size_t)(d4 + 0) * 2048] - e4.x;
      float d1 = xc[(size_t)(d4 + 1) * 2048] - e4.y;
      float d2 = xc[(size_t)(d4 + 2) * 2048] - e4.z;
      float d3 = xc[(size_t)(d4 + 3) * 2048] - e4.w;
      dsum = fmaf(d0, d0, dsum); dsum = fmaf(d1, d1, dsum);
      dsum = fmaf(d2, d2, dsum); dsum = fmaf(d3, d3, dsum);
    }
    d2s[cand * 64 + p] = dsum;
  }
  __syncthreads();
  if (tid < 64) {
    float bd = d2s[tid]; int bk = kcnd[tid];
#pragma unroll
    for (int cd = 1; cd < 4; ++cd) {
      float v = d2s[cd * 64 + tid];
      int k = kcnd[cd * 64 + tid];
      if (v < bd || (v == bd && k < bk)) { bd = v; bk = k; }
    }
    kfin[tid] = bk;
  }
  __syncthreads();

  // ---- E1: gather emb rows -> qt (slot-XOR swizzled), overlays ebuf ----
  {
    const int p = tid >> 2, q = tid & 3;
    const float* er = emb + (size_t)kfin[p] * 128 + q * 32;
#pragma unroll
    for (int j = 0; j < 8; ++j) {
      int slot = q * 8 + j;
      int sw = slot ^ (p & 31);
      *(float4*)(smem + p * 512 + sw * 16) = *(const float4*)&er[j * 4];
    }
  }
  __syncthreads();

  // ---- E2: lane = point; read qt along d (float4), coalesced stores along t
  float lsum = 0.f;
  {
    const int p = tid & 63, jb = tid >> 6;
    const float* xg = x + bOff + t0 + p;
    float* og = out + bOff + t0 + p;
#pragma unroll
    for (int i = 0; i < 8; ++i) {
      int slot = jb * 8 + i;
      int sw = slot ^ (p & 31);
      float4 q4 = *(const float4*)(smem + p * 512 + sw * 16);
      float qa[4] = {q4.x, q4.y, q4.z, q4.w};
      int dd = slot * 4;
#pragma unroll
      for (int i2 = 0; i2 < 4; ++i2) {
        float xv = xg[(size_t)(dd + i2) * 2048];
        float df = qa[i2] - xv;
        lsum = fmaf(df, df, lsum);
        og[(size_t)(dd + i2) * 2048] = qa[i2];
      }
    }
  }
#pragma unroll
  for (int off = 32; off; off >>= 1) lsum += __shfl_down(lsum, off, 64);
  if (lane == 0) wsum[w] = lsum;
  __syncthreads();
  if (tid == 0) partial[blk] = (wsum[0] + wsum[1]) + (wsum[2] + wsum[3]);
}

__global__ void vq_loss(const float* __restrict__ partial, float* __restrict__ out) {
  int lane = threadIdx.x;  // 64 threads, 512 partials
  float s = 0.f;
#pragma unroll
  for (int i = 0; i < 8; ++i) s += partial[i * 64 + lane];
#pragma unroll
  for (int off = 32; off; off >>= 1) s += __shfl_down(s, off, 64);
  if (lane == 0) out[4194304] = 1.25f * s / 4194304.0f;
}

extern "C" void kernel_launch(void* const* d_in, const int* in_sizes, int n_in,
                              void* d_out, int out_size, void* d_ws, size_t ws_size,
                              hipStream_t stream) {
  const float* x   = (const float*)d_in[0];   // [16,1,128,2048]
  const float* emb = (const float*)d_in[1];   // [1024,128]
  float* out = (float*)d_out;
  char* ws = (char*)d_ws;
  unsigned short* ehg = (unsigned short*)ws;              // 256 KB
  unsigned short* elg = (unsigned short*)(ws + 262144);   // 256 KB
  float* eh2g = (float*)(ws + 524288);                    // 4 KB
  float* partial = (float*)(ws + 528384);                 // 2 KB (512 floats)
  vq_prep<<<64, 256, 0, stream>>>(emb, ehg, elg, eh2g);
  vq_main<<<512, 256, 0, stream>>>(x, emb, ehg, elg, eh2g, out, partial);
  vq_loss<<<1, 64, 0, stream>>>(partial, out);
}

// Round 4
// 55.083 us; speedup vs baseline: 1.0633x; 1.0633x over previous
//
#include <hip/hip_runtime.h>
#include <math.h>
#include <float.h>

// VQ-VAE quantizer, round 4: fp16 one-sided split + per-wave codebook quarters.
// score(t,k) = x.eh_k - |e_k|^2/2, x = xh+xl (exact fp16 pair) -> 2 MFMAs/K-step.
// Error = x.el ~ 3e-3 (d2 scale); top-2 per quarter + exact fp32 rescore of all
// 8 candidates -> exact argmin decision (verified hedge from rounds 1-3).
// 512 blocks x 4 waves; wave = codebook quarter (256 codes), 64 points (2 sets).
// Per-wave private double-buffered chunks (32 codes), barrier-free main loop
// with counted s_waitcnt vmcnt(8) (T4).

typedef __attribute__((ext_vector_type(8))) _Float16 f16x8;
typedef __attribute__((ext_vector_type(16))) float f32x16;

#define CHUNK_BYTES 8192            // 32 codes x 128 d x 2B
#define EH2_OFF   65536             // 4 waves * 16384 chunk dbuf before this
#define KCND_OFF  69632             // 8*64 ints
#define D2S_OFF   71680             // 8*64 floats
#define KFIN_OFF  73728             // 64 ints
#define WSUM_OFF  73984             // 4 floats
#define SMEM_BYTES 74048

typedef __attribute__((address_space(1))) const void gas_t;
typedef __attribute__((address_space(3))) void las_t;
__device__ __forceinline__ void glds16(const void* g, void* l) {
  __builtin_amdgcn_global_load_lds((gas_t*)g, (las_t*)l, 16, 0, 0);
}

// ---- prep: emb f32 -> eh fp16 [1024][128] + eh2 = -0.5*|e|^2 (f32, exact) ----
__global__ __launch_bounds__(256)
void vq_prep(const float* __restrict__ emb, _Float16* __restrict__ ehg,
             float* __restrict__ eh2g) {
  const int tid = threadIdx.x;
  const int r = blockIdx.x * 16 + (tid >> 4);
  const int seg = tid & 15;
  const float* row = emb + (size_t)r * 128 + seg * 8;
  float4 f0 = *(const float4*)&row[0];
  float4 f1 = *(const float4*)&row[4];
  float fv[8] = {f0.x, f0.y, f0.z, f0.w, f1.x, f1.y, f1.z, f1.w};
  f16x8 H;
  float ssq = 0.f;
#pragma unroll
  for (int j = 0; j < 8; ++j) {
    float f = fv[j];
    ssq = fmaf(f, f, ssq);
    H[j] = (_Float16)f;             // RNE cvt
  }
  *(f16x8*)(ehg + (size_t)r * 128 + seg * 8) = H;
#pragma unroll
  for (int off = 1; off < 16; off <<= 1) ssq += __shfl_xor(ssq, off, 64);
  if (seg == 0) eh2g[r] = -0.5f * ssq;
}

__global__ __launch_bounds__(256, 2)
void vq_main(const float* __restrict__ x, const float* __restrict__ emb,
             const _Float16* __restrict__ ehg, const float* __restrict__ eh2g,
             float* __restrict__ out, float* __restrict__ partial) {
  __shared__ __align__(16) char smem[SMEM_BYTES];
  float* eh2s = (float*)(smem + EH2_OFF);
  int*   kcnd = (int*)(smem + KCND_OFF);
  float* d2s  = (float*)(smem + D2S_OFF);
  int*   kfin = (int*)(smem + KFIN_OFF);
  float* wsum = (float*)(smem + WSUM_OFF);

  const int tid = threadIdx.x;
  const int lane = tid & 63;
  const int w = tid >> 6;          // codebook quarter owned by this wave
  const int hf = lane >> 5;        // K-half of the mfma fragment
  const int c32 = lane & 31;       // mfma column = point within set
  const int blk = blockIdx.x;
  const int b = blk >> 5;
  const int t0 = (blk & 31) << 6;
  const size_t bOff = (size_t)b * 262144;   // b*128*2048

  char* bufs = smem + w * 16384;   // this wave's private chunk double-buffer
  const char* gq = (const char*)ehg + (size_t)w * 65536;  // quarter base

  // ---- issue eh2 quarter + chunk 0 + chunk 1 (async) ----
  glds16((const char*)eh2g + w * 1024 + lane * 16, smem + EH2_OFF + w * 1024);
#pragma unroll
  for (int c = 0; c < 2; ++c) {
#pragma unroll
    for (int i = 0; i < 8; ++i) {
      int o = i * 1024 + lane * 16;
      int s = o ^ (((o >> 8) & 15) << 4);   // inverse swizzle on global src
      glds16(gq + c * CHUNK_BYTES + s, bufs + c * CHUNK_BYTES + i * 1024);
    }
  }

  // ---- x B-fragments: fp32 global -> exact fp16 hi/lo pairs in regs ----
  f16x8 xh0[8], xl0[8], xh1[8], xl1[8];
  {
    const int dbase = hf * 8;
    const float* xp0 = x + bOff + t0 + c32;        // set 0: points t0..t0+31
    const float* xp1 = xp0 + 32;                   // set 1
#pragma unroll
    for (int ds = 0; ds < 8; ++ds) {
#pragma unroll
      for (int j = 0; j < 8; ++j) {
        size_t off = (size_t)(ds * 16 + dbase + j) * 2048;
        float f0 = xp0[off];
        _Float16 h0 = (_Float16)f0;
        xh0[ds][j] = h0;
        xl0[ds][j] = (_Float16)(f0 - (float)h0);
        float f1 = xp1[off];
        _Float16 h1 = (_Float16)f1;
        xh1[ds][j] = h1;
        xl1[ds][j] = (_Float16)(f1 - (float)h1);
      }
    }
  }

  asm volatile("s_waitcnt vmcnt(0)" ::: "memory");  // eh2 + chunks 0,1 landed

  float v1a = -FLT_MAX, v2a = -FLT_MAX, v1b = -FLT_MAX, v2b = -FLT_MAX;
  int k1a = 0, k2a = 0, k1b = 0, k2b = 0;

  for (int c = 0; c < 8; ++c) {
    asm volatile("s_waitcnt vmcnt(8)" ::: "memory");  // chunk c complete
    const char* buf = bufs + (c & 1) * CHUNK_BYTES;
    const int kb = w * 256 + c * 32;
    // C-init: acc[reg] = -0.5*|e_k|^2, k = kb + (reg&3) + 8*(reg>>2) + 4*hf
    f32x16 acc0, acc1;
#pragma unroll
    for (int q = 0; q < 4; ++q) {
      float4 v = *(const float4*)&eh2s[kb + 4 * hf + 8 * q];
      acc0[4 * q + 0] = v.x; acc0[4 * q + 1] = v.y;
      acc0[4 * q + 2] = v.z; acc0[4 * q + 3] = v.w;
    }
    acc1 = acc0;
    const int baseo = c32 * 256 + hf * 16;
    const int swz = (c32 & 15) << 4;
#pragma unroll
    for (int ds = 0; ds < 8; ++ds) {
      const int o = (baseo + ds * 32) ^ swz;
      f16x8 ea = *(const f16x8*)(buf + o);
      acc0 = __builtin_amdgcn_mfma_f32_32x32x16_f16(ea, xh0[ds], acc0, 0, 0, 0);
      acc0 = __builtin_amdgcn_mfma_f32_32x32x16_f16(ea, xl0[ds], acc0, 0, 0, 0);
      acc1 = __builtin_amdgcn_mfma_f32_32x32x16_f16(ea, xh1[ds], acc1, 0, 0, 0);
      acc1 = __builtin_amdgcn_mfma_f32_32x32x16_f16(ea, xl1[ds], acc1, 0, 0, 0);
    }
    // running top-2 per set (maximize; in-lane k ascending, strict > = first occ)
#pragma unroll
    for (int r = 0; r < 16; ++r) {
      int kk = kb + (r & 3) + 8 * (r >> 2) + 4 * hf;
      float s0 = acc0[r];
      bool q1 = s0 > v1a, q2 = s0 > v2a;
      v2a = fmaxf(fminf(s0, v1a), v2a);
      k2a = q1 ? k1a : (q2 ? kk : k2a);
      v1a = fmaxf(v1a, s0);
      k1a = q1 ? kk : k1a;
      float s1 = acc1[r];
      bool p1 = s1 > v1b, p2 = s1 > v2b;
      v2b = fmaxf(fminf(s1, v1b), v2b);
      k2b = p1 ? k1b : (p2 ? kk : k2b);
      v1b = fmaxf(v1b, s1);
      k1b = p1 ? kk : k1b;
    }
    if (c < 6) {   // stage chunk c+2 into the buffer just freed
#pragma unroll
      for (int i = 0; i < 8; ++i) {
        int o = i * 1024 + lane * 16;
        int s = o ^ (((o >> 8) & 15) << 4);
        glds16(gq + (c + 2) * CHUNK_BYTES + s,
               bufs + (c & 1) * CHUNK_BYTES + i * 1024);
      }
    }
  }

  // ---- merge hf halves -> per-point top-2 within this wave's quarter ----
  {
    // set 0
    float u1 = __shfl_xor(v1a, 32, 64); int j1 = __shfl_xor(k1a, 32, 64);
    float u2 = __shfl_xor(v2a, 32, 64); int j2 = __shfl_xor(k2a, 32, 64);
    bool a = (u1 > v1a) || (u1 == v1a && j1 < k1a);
    int w1k = a ? j1 : k1a;
    float lsv = a ? v1a : u1; int lsk = a ? k1a : j1;
    float wsv = a ? u2 : v2a; int wsk = a ? j2 : k2a;
    bool bb = (lsv > wsv) || (lsv == wsv && lsk < wsk);
    int w2k = bb ? lsk : wsk;
    if (hf == 0) {
      kcnd[(w * 2 + 0) * 64 + c32] = w1k;
      kcnd[(w * 2 + 1) * 64 + c32] = w2k;
    }
    // set 1
    u1 = __shfl_xor(v1b, 32, 64); j1 = __shfl_xor(k1b, 32, 64);
    u2 = __shfl_xor(v2b, 32, 64); j2 = __shfl_xor(k2b, 32, 64);
    a = (u1 > v1b) || (u1 == v1b && j1 < k1b);
    w1k = a ? j1 : k1b;
    lsv = a ? v1b : u1; lsk = a ? k1b : j1;
    wsv = a ? u2 : v2b; wsk = a ? j2 : k2b;
    bb = (lsv > wsv) || (lsv == wsv && lsk < wsk);
    w2k = bb ? lsk : wsk;
    if (hf == 0) {
      kcnd[(w * 2 + 0) * 64 + 32 + c32] = w1k;
      kcnd[(w * 2 + 1) * 64 + 32 + c32] = w2k;
    }
  }
  __syncthreads();

  // ---- exact fp32 rescore of 8 candidates: thread = (point, cand) x2 ----
#pragma unroll
  for (int rep = 0; rep < 2; ++rep) {
    const int p = tid & 63, cand = rep * 4 + (tid >> 6);
    const int kc = kcnd[cand * 64 + p];
    const float* xc = x + bOff + t0 + p;
    const float* er = emb + (size_t)kc * 128;
    float dsum = 0.f;
#pragma unroll 4
    for (int d4 = 0; d4 < 128; d4 += 4) {
      float4 e4 = *(const float4*)&er[d4];
      float d0 = xc[(size_t)(d4 + 0) * 2048] - e4.x;
      float d1 = xc[(size_t)(d4 + 1) * 2048] - e4.y;
      float d2 = xc[(size_t)(d4 + 2) * 2048] - e4.z;
      float d3 = xc[(size_t)(d4 + 3) * 2048] - e4.w;
      dsum = fmaf(d0, d0, dsum); dsum = fmaf(d1, d1, dsum);
      dsum = fmaf(d2, d2, dsum); dsum = fmaf(d3, d3, dsum);
    }
    d2s[cand * 64 + p] = dsum;
  }
  __syncthreads();
  if (tid < 64) {
    float bd = d2s[tid]; int bk = kcnd[tid];
#pragma unroll
    for (int cd = 1; cd < 8; ++cd) {
      float v = d2s[cd * 64 + tid];
      int k = kcnd[cd * 64 + tid];
      if (v < bd || (v == bd && k < bk)) { bd = v; bk = k; }
    }
    kfin[tid] = bk;
  }
  __syncthreads();

  // ---- E1: gather emb rows -> qt (slot-XOR swizzled), overlays chunk bufs ----
  {
    const int p = tid >> 2, q = tid & 3;
    const float* er = emb + (size_t)kfin[p] * 128 + q * 32;
#pragma unroll
    for (int j = 0; j < 8; ++j) {
      int slot = q * 8 + j;
      int sw = slot ^ (p & 31);
      *(float4*)(smem + p * 512 + sw * 16) = *(const float4*)&er[j * 4];
    }
  }
  __syncthreads();

  // ---- E2: lane = point; read qt along d, coalesced stores along t ----
  float lsum = 0.f;
  {
    const int p = tid & 63, jb = tid >> 6;
    const float* xg = x + bOff + t0 + p;
    float* og = out + bOff + t0 + p;
#pragma unroll
    for (int i = 0; i < 8; ++i) {
      int slot = jb * 8 + i;
      int sw = slot ^ (p & 31);
      float4 q4 = *(const float4*)(smem + p * 512 + sw * 16);
      float qa[4] = {q4.x, q4.y, q4.z, q4.w};
      int dd = slot * 4;
#pragma unroll
      for (int i2 = 0; i2 < 4; ++i2) {
        float xv = xg[(size_t)(dd + i2) * 2048];
        float df = qa[i2] - xv;
        lsum = fmaf(df, df, lsum);
        og[(size_t)(dd + i2) * 2048] = qa[i2];
      }
    }
  }
#pragma unroll
  for (int off = 32; off; off >>= 1) lsum += __shfl_down(lsum, off, 64);
  if (lane == 0) wsum[w] = lsum;
  __syncthreads();
  if (tid == 0) partial[blk] = (wsum[0] + wsum[1]) + (wsum[2] + wsum[3]);
}

__global__ void vq_loss(const float* __restrict__ partial, float* __restrict__ out) {
  int lane = threadIdx.x;  // 64 threads, 512 partials
  float s = 0.f;
#pragma unroll
  for (int i = 0; i < 8; ++i) s += partial[i * 64 + lane];
#pragma unroll
  for (int off = 32; off; off >>= 1) s += __shfl_down(s, off, 64);
  if (lane == 0) out[4194304] = 1.25f * s / 4194304.0f;
}

extern "C" void kernel_launch(void* const* d_in, const int* in_sizes, int n_in,
                              void* d_out, int out_size, void* d_ws, size_t ws_size,
                              hipStream_t stream) {
  const float* x   = (const float*)d_in[0];   // [16,1,128,2048]
  const float* emb = (const float*)d_in[1];   // [1024,128]
  float* out = (float*)d_out;
  char* ws = (char*)d_ws;
  _Float16* ehg = (_Float16*)ws;              // 256 KB
  float* eh2g = (float*)(ws + 262144);        // 4 KB
  float* partial = (float*)(ws + 266240);     // 2 KB (512 floats)
  vq_prep<<<64, 256, 0, stream>>>(emb, ehg, eh2g);
  vq_main<<<512, 256, 0, stream>>>(x, emb, ehg, eh2g, out, partial);
  vq_loss<<<1, 64, 0, stream>>>(partial, out);
}